// Round 8
// baseline (228.460 us; speedup 1.0000x reference)
//
#include <hip/hip_runtime.h>

#define NSP 200000
#define NE  1200000
#define DIM 128
#define NTILE 12500        // NSP/16
#define NBKT  782          // ceil(NSP/256) row-range buckets
#define MAXE  2560         // per-bucket edge capacity for LDS sort (mean 1536, sigma 39)

#define CAST_B 12500
#define WT_B   192
#define CNT_B  586

#define FIN_B  262         // k_final blocks: 262*16 waves*3 tiles >= 12500, ~1 generation

typedef __attribute__((ext_vector_type(8))) short short8;
typedef __attribute__((ext_vector_type(4))) short short4v;
typedef __attribute__((ext_vector_type(4))) float f32x4;

// ---- workspace byte offsets (16B aligned) ----
#define OFF_BB     0               // (NBKT+1)*4
#define OFF_CUR    3136            // NBKT*4
#define OFF_BCNT   6272            // NBKT*4
#define OFF_PAIRS  9408            // NE*4 packed (lr<<18)|col; sorted in place by k_sort
#define OFF_ROWPTR 4809408         // (NSP+1)*4
#define OFF_WT     5609424         // 3*128*128*2 bf16
#define OFF_UB     5707728         // NSP*128*2 bf16 u
#define OFF_AGGB   56907728        // NSP*128*2 bf16 agg (normalized)

__device__ __forceinline__ unsigned f2bf(float x){
  union { float f; unsigned u; } v; v.f = x;
  unsigned r = v.u + 0x7FFFu + ((v.u >> 16) & 1u);   // RNE
  return r >> 16;
}
__device__ __forceinline__ float bflo(unsigned v){ union{unsigned u;float f;}x; x.u = v << 16; return x.f; }
__device__ __forceinline__ float bfhi(unsigned v){ union{unsigned u;float f;}x; x.u = v & 0xffff0000u; return x.f; }
__device__ __forceinline__ float lrelu(float x){ return x > 0.f ? x : 0.2f * x; }

// swizzled byte offset inside a [rows][128] bf16 LDS tile (row stride 256B).
// full 4-bit slot XOR: 16 16B-slots/row, slot ^= row&15 -> 4 lanes/slot on af reads
__device__ __forceinline__ int lbyte(int row, int kb){
  return row * 256 + (kb ^ ((row & 15) << 4));
}

// ---- prep: cast u->bf16 | transpose W->bf16 W^T | bucket histogram, by block range ----
__global__ void k_prep(const float* __restrict__ u, unsigned short* __restrict__ ub,
                       const float* __restrict__ W1, const float* __restrict__ W2,
                       const float* __restrict__ Wp, unsigned short* __restrict__ wt,
                       const int* __restrict__ row, unsigned* __restrict__ cnt){
  __shared__ unsigned hist[NBKT];
  int bid = blockIdx.x;
  if (bid < CAST_B){
    size_t i = (size_t)bid * 256 + threadIdx.x;
    const float4* p = (const float4*)(u + i * 8);
    float4 x0 = p[0], x1 = p[1];
    short8 v;
    v[0]=(short)f2bf(x0.x); v[1]=(short)f2bf(x0.y); v[2]=(short)f2bf(x0.z); v[3]=(short)f2bf(x0.w);
    v[4]=(short)f2bf(x1.x); v[5]=(short)f2bf(x1.y); v[6]=(short)f2bf(x1.z); v[7]=(short)f2bf(x1.w);
    *(short8*)(ub + i * 8) = v;
  } else if (bid < CAST_B + WT_B){
    int i = (bid - CAST_B) * 256 + threadIdx.x;
    int m = i >> 14, e = i & 16383;
    int k = e >> 7, c = e & 127;
    const float* W = (m == 0) ? W1 : (m == 1) ? W2 : Wp;
    wt[m * 16384 + c * 128 + k] = (unsigned short)f2bf(W[e]);
  } else {
    int cb = bid - CAST_B - WT_B;
    for (int i = threadIdx.x; i < NBKT; i += 256) hist[i] = 0;
    __syncthreads();
    #pragma unroll
    for (int j = 0; j < 8; ++j){
      int i = cb * 2048 + j * 256 + threadIdx.x;
      if (i < NE) atomicAdd(&hist[row[i] >> 8], 1u);
    }
    __syncthreads();
    for (int i = threadIdx.x; i < NBKT; i += 256){
      unsigned v = hist[i];
      if (v) atomicAdd(&cnt[i], v);
    }
  }
}

// ---- exclusive scan of NBKT counts (1 block) -> bb, cur ----
__global__ void k_bscan(const unsigned* __restrict__ cnt, unsigned* __restrict__ bb,
                        unsigned* __restrict__ cur){
  __shared__ unsigned wsum[4];
  int t = threadIdx.x, lane = t & 63, w = t >> 6;
  unsigned c4[4], s = 0;
  #pragma unroll
  for (int j = 0; j < 4; ++j){
    int idx = t * 4 + j;
    c4[j] = (idx < NBKT) ? cnt[idx] : 0u;
    s += c4[j];
  }
  unsigned inc = s;
  #pragma unroll
  for (int off = 1; off < 64; off <<= 1){
    unsigned n = __shfl_up(inc, (unsigned)off, 64);
    if (lane >= off) inc += n;
  }
  if (lane == 63) wsum[w] = inc;
  __syncthreads();
  unsigned prior = 0;
  for (int i = 0; i < w; ++i) prior += wsum[i];
  unsigned excl = prior + (inc - s);
  #pragma unroll
  for (int j = 0; j < 4; ++j){
    int idx = t * 4 + j;
    if (idx < NBKT){
      bb[idx] = excl; cur[idx] = excl;
      excl += c4[j];
      if (idx == NBKT - 1) bb[NBKT] = excl;
    }
  }
}

// ---- bin edges into bucket regions (block-batched cursor grabs) ----
__global__ void k_bfill(const int* __restrict__ row, const int* __restrict__ col,
                        unsigned* __restrict__ cur, unsigned* __restrict__ pairs){
  __shared__ unsigned hist[NBKT], base[NBKT];
  for (int i = threadIdx.x; i < NBKT; i += 512) hist[i] = 0;
  __syncthreads();
  int r[16], c[16];
  #pragma unroll
  for (int j = 0; j < 16; ++j){
    int i = blockIdx.x * 8192 + j * 512 + threadIdx.x;
    r[j] = -1;
    if (i < NE){ r[j] = row[i]; c[j] = col[i]; atomicAdd(&hist[r[j] >> 8], 1u); }
  }
  __syncthreads();
  for (int i = threadIdx.x; i < NBKT; i += 512){
    unsigned n = hist[i];
    base[i] = n ? atomicAdd(&cur[i], n) : 0u;
    hist[i] = 0;
  }
  __syncthreads();
  #pragma unroll
  for (int j = 0; j < 16; ++j){
    if (r[j] >= 0){
      int b = r[j] >> 8;
      unsigned pos = base[b] + atomicAdd(&hist[b], 1u);
      pairs[pos] = ((unsigned)(r[j] & 255) << 18) | (unsigned)c[j];
    }
  }
}

// ---- per bucket: counting-sort pairs by local row IN PLACE, emit global CSR rowptr ----
__launch_bounds__(256)
__global__ void k_sort(const unsigned* __restrict__ bb,
                       unsigned* __restrict__ pairs,
                       unsigned* __restrict__ rowptr){
  __shared__ unsigned raw[MAXE], srt[MAXE];
  __shared__ unsigned hist[256], start[257], cur[256];
  __shared__ unsigned wsum[4];
  const int b = blockIdx.x, t = threadIdx.x;
  const int lane = t & 63, w = t >> 6;
  const unsigned base0 = bb[b], cnt = bb[b + 1] - base0;
  hist[t] = 0; cur[t] = 0;
  __syncthreads();

  if (cnt <= MAXE){
    for (unsigned i = t; i < cnt; i += 256){
      unsigned p = pairs[base0 + i];
      raw[i] = p;
      atomicAdd(&hist[p >> 18], 1u);
    }
  } else {
    for (unsigned i = t; i < cnt; i += 256)
      atomicAdd(&hist[pairs[base0 + i] >> 18], 1u);
  }
  __syncthreads();
  unsigned v = hist[t], inc = v;
  #pragma unroll
  for (int off = 1; off < 64; off <<= 1){
    unsigned n = __shfl_up(inc, (unsigned)off, 64);
    if (lane >= off) inc += n;
  }
  if (lane == 63) wsum[w] = inc;
  __syncthreads();
  unsigned prior = 0;
  for (int i = 0; i < w; ++i) prior += wsum[i];
  start[t] = prior + inc - v;
  if (t == 255) start[256] = prior + inc;
  __syncthreads();

  {
    int idx = b * 256 + t;
    if (idx <= NSP) rowptr[idx] = base0 + start[t];
  }

  if (cnt <= MAXE){
    for (unsigned i = t; i < cnt; i += 256){
      unsigned p = raw[i], lr = p >> 18;
      unsigned slot = start[lr] + atomicAdd(&cur[lr], 1u);
      srt[slot] = p & 0x3FFFFu;
    }
    __syncthreads();
    for (unsigned i = t; i < cnt; i += 256) pairs[base0 + i] = srt[i];
  }
  // overflow buckets (statistically unreachable): left unsorted; gather falls back
}

// ---- gather: 4 spots per wave, 16 lanes x uint4 (16B) per spot row ----
__launch_bounds__(256)
__global__ void k_gather(const unsigned short* __restrict__ ub,
                         const unsigned* __restrict__ bb,
                         const unsigned* __restrict__ rowptr,
                         const unsigned* __restrict__ pairs,
                         unsigned short* __restrict__ aggb){
  const int wid = (blockIdx.x * 256 + threadIdx.x) >> 6;   // 0..49999
  const int lane = threadIdx.x & 63;
  const int g = lane >> 4, l = lane & 15;
  const int s = wid * 4 + g;                               // spot, < NSP exactly
  const int b = s >> 8;
  const unsigned e0 = rowptr[s], e1 = rowptr[s + 1];
  int deg = (int)(e1 - e0);
  const unsigned bc = bb[b + 1] - bb[b];
  float a[8];
  #pragma unroll
  for (int q = 0; q < 8; ++q) a[q] = 0.f;
  const unsigned short* ubl = ub + (size_t)l * 8;

  if (bc <= MAXE){
    for (int base = 0; base < deg; base += 4){
      int ii = base + (l & 3);
      int myidx = (int)(pairs[e0 + min(ii, deg - 1)] & 0x3FFFFu);
      int cc[4]; float m[4];
      #pragma unroll
      for (int q = 0; q < 4; ++q){
        cc[q] = __shfl(myidx, (g << 4) | q, 64);
        m[q] = (base + q < deg) ? 1.f : 0.f;
      }
      uint4 v[4];
      #pragma unroll
      for (int q = 0; q < 4; ++q)
        v[q] = *(const uint4*)(ubl + (size_t)cc[q] * DIM);
      #pragma unroll
      for (int q = 0; q < 4; ++q){
        a[0]=fmaf(m[q],bflo(v[q].x),a[0]); a[1]=fmaf(m[q],bfhi(v[q].x),a[1]);
        a[2]=fmaf(m[q],bflo(v[q].y),a[2]); a[3]=fmaf(m[q],bfhi(v[q].y),a[3]);
        a[4]=fmaf(m[q],bflo(v[q].z),a[4]); a[5]=fmaf(m[q],bfhi(v[q].z),a[5]);
        a[6]=fmaf(m[q],bflo(v[q].w),a[6]); a[7]=fmaf(m[q],bfhi(v[q].w),a[7]);
      }
    }
  } else {
    // unsorted overflow bucket: deterministic in-order scan filter
    unsigned p0 = bb[b], p1 = bb[b + 1];
    int lr = s & 255; deg = 0;
    for (unsigned e = p0; e < p1; ++e){
      unsigned p = pairs[e];
      if ((int)(p >> 18) == lr){
        ++deg;
        uint4 v = *(const uint4*)(ubl + (size_t)(p & 0x3FFFFu) * DIM);
        a[0]+=bflo(v.x); a[1]+=bfhi(v.x); a[2]+=bflo(v.y); a[3]+=bfhi(v.y);
        a[4]+=bflo(v.z); a[5]+=bfhi(v.z); a[6]+=bflo(v.w); a[7]+=bfhi(v.w);
      }
    }
  }
  float scl = deg ? 1.f / (float)deg : 0.f;
  uint4 o;
  o.x = f2bf(a[0]*scl) | (f2bf(a[1]*scl) << 16);
  o.y = f2bf(a[2]*scl) | (f2bf(a[3]*scl) << 16);
  o.z = f2bf(a[4]*scl) | (f2bf(a[5]*scl) << 16);
  o.w = f2bf(a[6]*scl) | (f2bf(a[7]*scl) << 16);
  *(uint4*)(aggb + (size_t)s * DIM + l * 8) = o;
}

// ---- fused MLP: persistent-lite — 262 blocks (~1 generation), weights staged once,
//      each wave runs 3 CONTIGUOUS tiles sequentially (registers reused, locality kept)
__launch_bounds__(1024)
__global__ void k_final(const unsigned short* __restrict__ ub,
                        const float* __restrict__ b1,
                        const float* __restrict__ b2,
                        const float* __restrict__ bp,
                        const unsigned short* __restrict__ wt,
                        const unsigned short* __restrict__ aggb,
                        float* __restrict__ out){
  __shared__ __align__(16) char smem[163840];   // 3x32KB W^T + 16x4KB h

  // stage all three W^T into LDS (bf16, XOR-swizzled rows)
  for (int c = threadIdx.x; c < 6144; c += 1024){
    int m = c >> 11, cc = c & 2047;
    int i = cc >> 4, kb = (cc & 15) << 4;
    short8 v = *(const short8*)(wt + m * 16384 + i * 128 + (kb >> 1));
    *(short8*)(smem + m * 32768 + lbyte(i, kb)) = v;
  }
  __syncthreads();

  const int wid = threadIdx.x >> 6, lane = threadIdx.x & 63;
  const int l15 = lane & 15, kg = lane >> 4;
  char* hbuf = smem + 98304 + wid * 4096;
  const int slot = blockIdx.x * 16 + wid;          // 0..4191

  #pragma unroll 1
  for (int ti = 0; ti < 3; ++ti){
    const int tile = slot * 3 + ti;                // contiguous per wave
    if (tile >= NTILE) break;
    const int s = tile * 16 + l15;
    const size_t srow = (size_t)s * DIM;

    f32x4 acc[8], hh[8];
    #pragma unroll
    for (int ft = 0; ft < 8; ++ft){ acc[ft] = (f32x4){0.f,0.f,0.f,0.f}; hh[ft] = (f32x4){0.f,0.f,0.f,0.f}; }

    // ---- stage C: acc = Wp^T @ aggn^T ----
    #pragma unroll
    for (int ks = 0; ks < 4; ++ks){
      short8 bf = *(const short8*)(aggb + srow + ks * 32 + kg * 8);
      #pragma unroll
      for (int ft = 0; ft < 8; ++ft){
        short8 af = *(const short8*)(smem + 2 * 32768 + lbyte(ft * 16 + l15, ks * 64 + kg * 16));
        acc[ft] = __builtin_amdgcn_mfma_f32_16x16x32_bf16(af, bf, acc[ft], 0, 0, 0);
      }
    }
    #pragma unroll
    for (int ft = 0; ft < 8; ++ft){
      int f0 = ft * 16 + kg * 4;
      float4 bv = *(const float4*)(bp + f0);
      acc[ft][0] = lrelu(acc[ft][0] + bv.x);
      acc[ft][1] = lrelu(acc[ft][1] + bv.y);
      acc[ft][2] = lrelu(acc[ft][2] + bv.z);
      acc[ft][3] = lrelu(acc[ft][3] + bv.w);
    }

    // ---- stage A: hh = W1^T @ u^T ----
    #pragma unroll
    for (int ks = 0; ks < 4; ++ks){
      short8 bf = *(const short8*)(ub + srow + ks * 32 + kg * 8);
      #pragma unroll
      for (int ft = 0; ft < 8; ++ft){
        short8 af = *(const short8*)(smem + 0 * 32768 + lbyte(ft * 16 + l15, ks * 64 + kg * 16));
        hh[ft] = __builtin_amdgcn_mfma_f32_16x16x32_bf16(af, bf, hh[ft], 0, 0, 0);
      }
    }
    #pragma unroll
    for (int ft = 0; ft < 8; ++ft){
      int f0 = ft * 16 + kg * 4;
      float4 bv = *(const float4*)(b1 + f0);
      short4v hv;
      hv[0] = (short)f2bf(lrelu(hh[ft][0] + bv.x));
      hv[1] = (short)f2bf(lrelu(hh[ft][1] + bv.y));
      hv[2] = (short)f2bf(lrelu(hh[ft][2] + bv.z));
      hv[3] = (short)f2bf(lrelu(hh[ft][3] + bv.w));
      *(short4v*)(hbuf + lbyte(l15, 2 * f0)) = hv;
    }

    // ---- stage B: acc += W2^T @ h^T ----
    #pragma unroll
    for (int ks = 0; ks < 4; ++ks){
      short8 bf = *(const short8*)(hbuf + lbyte(l15, ks * 64 + kg * 16));
      #pragma unroll
      for (int ft = 0; ft < 8; ++ft){
        short8 af = *(const short8*)(smem + 1 * 32768 + lbyte(ft * 16 + l15, ks * 64 + kg * 16));
        acc[ft] = __builtin_amdgcn_mfma_f32_16x16x32_bf16(af, bf, acc[ft], 0, 0, 0);
      }
    }

    // ---- epilogue ----
    #pragma unroll
    for (int ft = 0; ft < 8; ++ft){
      int f0 = ft * 16 + kg * 4;
      float4 bv = *(const float4*)(b2 + f0);
      f32x4 o = acc[ft];
      o[0] += bv.x; o[1] += bv.y; o[2] += bv.z; o[3] += bv.w;
      *(f32x4*)(out + srow + f0) = o;
    }
  }
}

extern "C" void kernel_launch(void* const* d_in, const int* in_sizes, int n_in,
                              void* d_out, int out_size, void* d_ws, size_t ws_size,
                              hipStream_t stream){
  (void)in_sizes; (void)n_in; (void)out_size; (void)ws_size;
  const float* u  = (const float*)d_in[0];
  const float* W1 = (const float*)d_in[1];
  const float* b1 = (const float*)d_in[2];
  const float* W2 = (const float*)d_in[3];
  const float* b2 = (const float*)d_in[4];
  const float* Wp = (const float*)d_in[5];
  const float* bp = (const float*)d_in[6];
  const int* row  = (const int*)d_in[7];
  const int* col  = (const int*)d_in[8];
  char* ws = (char*)d_ws;
  unsigned* bb     = (unsigned*)(ws + OFF_BB);
  unsigned* cur    = (unsigned*)(ws + OFF_CUR);
  unsigned* bcnt   = (unsigned*)(ws + OFF_BCNT);
  unsigned* pairs  = (unsigned*)(ws + OFF_PAIRS);
  unsigned* rowptr = (unsigned*)(ws + OFF_ROWPTR);
  unsigned short* wt    = (unsigned short*)(ws + OFF_WT);
  unsigned short* ubp   = (unsigned short*)(ws + OFF_UB);
  unsigned short* aggbp = (unsigned short*)(ws + OFF_AGGB);
  float* out = (float*)d_out;

  hipMemsetAsync(ws + OFF_BCNT, 0, 3136, stream);
  k_prep  <<<CAST_B + WT_B + CNT_B, 256, 0, stream>>>(u, ubp, W1, W2, Wp, wt, row, bcnt);
  k_bscan <<<1, 256, 0, stream>>>(bcnt, bb, cur);
  k_bfill <<<147, 512, 0, stream>>>(row, col, cur, pairs);
  k_sort  <<<NBKT, 256, 0, stream>>>(bb, pairs, rowptr);
  k_gather<<<12500, 256, 0, stream>>>(ubp, bb, rowptr, pairs, aggbp);
  k_final <<<FIN_B, 1024, 0, stream>>>(ubp, b1, b2, bp, wt, aggbp, out);
}

// Round 9
// 223.227 us; speedup vs baseline: 1.0234x; 1.0234x over previous
//
#include <hip/hip_runtime.h>

#define NSP 200000
#define NE  1200000
#define DIM 128
#define NTILE 12500        // NSP/16
#define NBKT  782          // ceil(NSP/256) row-range buckets
#define MAXE  2560         // per-bucket edge capacity for LDS sort (mean 1536, sigma 39)

#define CAST_B 12500
#define WT_B   192
#define CNT_B  586

typedef __attribute__((ext_vector_type(8))) short short8;
typedef __attribute__((ext_vector_type(4))) short short4v;
typedef __attribute__((ext_vector_type(4))) float f32x4;

// ---- workspace byte offsets (16B aligned) ----
#define OFF_BB     0               // (NBKT+1)*4
#define OFF_CUR    3136            // NBKT*4
#define OFF_BCNT   6272            // NBKT*4
#define OFF_PAIRS  9408            // NE*4 packed (lr<<18)|col; sorted in place by k_sort
#define OFF_ROWPTR 4809408         // (NSP+1)*4
#define OFF_WT     5609424         // 3*128*128*2 bf16
#define OFF_UB     5707728         // NSP*128*2 bf16 u; OVERWRITTEN with h by k_h
#define OFF_AGGB   56907728        // NSP*128*2 bf16 agg (normalized)

__device__ __forceinline__ unsigned f2bf(float x){
  union { float f; unsigned u; } v; v.f = x;
  unsigned r = v.u + 0x7FFFu + ((v.u >> 16) & 1u);   // RNE
  return r >> 16;
}
__device__ __forceinline__ float bflo(unsigned v){ union{unsigned u;float f;}x; x.u = v << 16; return x.f; }
__device__ __forceinline__ float bfhi(unsigned v){ union{unsigned u;float f;}x; x.u = v & 0xffff0000u; return x.f; }
__device__ __forceinline__ float lrelu(float x){ return x > 0.f ? x : 0.2f * x; }

// swizzled byte offset inside a [rows][128] bf16 LDS tile (row stride 256B)
// full 4-bit slot XOR (R8: bank conflicts 5.4M -> 400K)
__device__ __forceinline__ int lbyte(int row, int kb){
  return row * 256 + (kb ^ ((row & 15) << 4));
}

// ---- prep: cast u->bf16 | transpose W->bf16 W^T | bucket histogram, by block range ----
__global__ void k_prep(const float* __restrict__ u, unsigned short* __restrict__ ub,
                       const float* __restrict__ W1, const float* __restrict__ W2,
                       const float* __restrict__ Wp, unsigned short* __restrict__ wt,
                       const int* __restrict__ row, unsigned* __restrict__ cnt){
  __shared__ unsigned hist[NBKT];
  int bid = blockIdx.x;
  if (bid < CAST_B){
    size_t i = (size_t)bid * 256 + threadIdx.x;
    const float4* p = (const float4*)(u + i * 8);
    float4 x0 = p[0], x1 = p[1];
    short8 v;
    v[0]=(short)f2bf(x0.x); v[1]=(short)f2bf(x0.y); v[2]=(short)f2bf(x0.z); v[3]=(short)f2bf(x0.w);
    v[4]=(short)f2bf(x1.x); v[5]=(short)f2bf(x1.y); v[6]=(short)f2bf(x1.z); v[7]=(short)f2bf(x1.w);
    *(short8*)(ub + i * 8) = v;
  } else if (bid < CAST_B + WT_B){
    int i = (bid - CAST_B) * 256 + threadIdx.x;
    int m = i >> 14, e = i & 16383;
    int k = e >> 7, c = e & 127;
    const float* W = (m == 0) ? W1 : (m == 1) ? W2 : Wp;
    wt[m * 16384 + c * 128 + k] = (unsigned short)f2bf(W[e]);
  } else {
    int cb = bid - CAST_B - WT_B;
    for (int i = threadIdx.x; i < NBKT; i += 256) hist[i] = 0;
    __syncthreads();
    #pragma unroll
    for (int j = 0; j < 8; ++j){
      int i = cb * 2048 + j * 256 + threadIdx.x;
      if (i < NE) atomicAdd(&hist[row[i] >> 8], 1u);
    }
    __syncthreads();
    for (int i = threadIdx.x; i < NBKT; i += 256){
      unsigned v = hist[i];
      if (v) atomicAdd(&cnt[i], v);
    }
  }
}

// ---- exclusive scan of NBKT counts (1 block) -> bb, cur ----
__global__ void k_bscan(const unsigned* __restrict__ cnt, unsigned* __restrict__ bb,
                        unsigned* __restrict__ cur){
  __shared__ unsigned wsum[4];
  int t = threadIdx.x, lane = t & 63, w = t >> 6;
  unsigned c4[4], s = 0;
  #pragma unroll
  for (int j = 0; j < 4; ++j){
    int idx = t * 4 + j;
    c4[j] = (idx < NBKT) ? cnt[idx] : 0u;
    s += c4[j];
  }
  unsigned inc = s;
  #pragma unroll
  for (int off = 1; off < 64; off <<= 1){
    unsigned n = __shfl_up(inc, (unsigned)off, 64);
    if (lane >= off) inc += n;
  }
  if (lane == 63) wsum[w] = inc;
  __syncthreads();
  unsigned prior = 0;
  for (int i = 0; i < w; ++i) prior += wsum[i];
  unsigned excl = prior + (inc - s);
  #pragma unroll
  for (int j = 0; j < 4; ++j){
    int idx = t * 4 + j;
    if (idx < NBKT){
      bb[idx] = excl; cur[idx] = excl;
      excl += c4[j];
      if (idx == NBKT - 1) bb[NBKT] = excl;
    }
  }
}

// ---- bin edges into bucket regions (block-batched cursor grabs) ----
__global__ void k_bfill(const int* __restrict__ row, const int* __restrict__ col,
                        unsigned* __restrict__ cur, unsigned* __restrict__ pairs){
  __shared__ unsigned hist[NBKT], base[NBKT];
  for (int i = threadIdx.x; i < NBKT; i += 512) hist[i] = 0;
  __syncthreads();
  int r[16], c[16];
  #pragma unroll
  for (int j = 0; j < 16; ++j){
    int i = blockIdx.x * 8192 + j * 512 + threadIdx.x;
    r[j] = -1;
    if (i < NE){ r[j] = row[i]; c[j] = col[i]; atomicAdd(&hist[r[j] >> 8], 1u); }
  }
  __syncthreads();
  for (int i = threadIdx.x; i < NBKT; i += 512){
    unsigned n = hist[i];
    base[i] = n ? atomicAdd(&cur[i], n) : 0u;
    hist[i] = 0;
  }
  __syncthreads();
  #pragma unroll
  for (int j = 0; j < 16; ++j){
    if (r[j] >= 0){
      int b = r[j] >> 8;
      unsigned pos = base[b] + atomicAdd(&hist[b], 1u);
      pairs[pos] = ((unsigned)(r[j] & 255) << 18) | (unsigned)c[j];
    }
  }
}

// ---- per bucket: counting-sort pairs by local row IN PLACE, emit global CSR rowptr ----
__launch_bounds__(256)
__global__ void k_sort(const unsigned* __restrict__ bb,
                       unsigned* __restrict__ pairs,
                       unsigned* __restrict__ rowptr){
  __shared__ unsigned raw[MAXE], srt[MAXE];
  __shared__ unsigned hist[256], start[257], cur[256];
  __shared__ unsigned wsum[4];
  const int b = blockIdx.x, t = threadIdx.x;
  const int lane = t & 63, w = t >> 6;
  const unsigned base0 = bb[b], cnt = bb[b + 1] - base0;
  hist[t] = 0; cur[t] = 0;
  __syncthreads();

  if (cnt <= MAXE){
    for (unsigned i = t; i < cnt; i += 256){
      unsigned p = pairs[base0 + i];
      raw[i] = p;
      atomicAdd(&hist[p >> 18], 1u);
    }
  } else {
    for (unsigned i = t; i < cnt; i += 256)
      atomicAdd(&hist[pairs[base0 + i] >> 18], 1u);
  }
  __syncthreads();
  unsigned v = hist[t], inc = v;
  #pragma unroll
  for (int off = 1; off < 64; off <<= 1){
    unsigned n = __shfl_up(inc, (unsigned)off, 64);
    if (lane >= off) inc += n;
  }
  if (lane == 63) wsum[w] = inc;
  __syncthreads();
  unsigned prior = 0;
  for (int i = 0; i < w; ++i) prior += wsum[i];
  start[t] = prior + inc - v;
  if (t == 255) start[256] = prior + inc;
  __syncthreads();

  {
    int idx = b * 256 + t;
    if (idx <= NSP) rowptr[idx] = base0 + start[t];
  }

  if (cnt <= MAXE){
    for (unsigned i = t; i < cnt; i += 256){
      unsigned p = raw[i], lr = p >> 18;
      unsigned slot = start[lr] + atomicAdd(&cur[lr], 1u);
      srt[slot] = p & 0x3FFFFu;
    }
    __syncthreads();
    for (unsigned i = t; i < cnt; i += 256) pairs[base0 + i] = srt[i];
  }
  // overflow buckets (statistically unreachable): left unsorted; gather falls back
}

// ---- gather: 4 spots per wave, 16 lanes x uint4 (16B) per spot row ----
__launch_bounds__(256)
__global__ void k_gather(const unsigned short* __restrict__ ub,
                         const unsigned* __restrict__ bb,
                         const unsigned* __restrict__ rowptr,
                         const unsigned* __restrict__ pairs,
                         unsigned short* __restrict__ aggb){
  const int wid = (blockIdx.x * 256 + threadIdx.x) >> 6;   // 0..49999
  const int lane = threadIdx.x & 63;
  const int g = lane >> 4, l = lane & 15;
  const int s = wid * 4 + g;                               // spot, < NSP exactly
  const int b = s >> 8;
  const unsigned e0 = rowptr[s], e1 = rowptr[s + 1];
  int deg = (int)(e1 - e0);
  const unsigned bc = bb[b + 1] - bb[b];
  float a[8];
  #pragma unroll
  for (int q = 0; q < 8; ++q) a[q] = 0.f;
  const unsigned short* ubl = ub + (size_t)l * 8;

  if (bc <= MAXE){
    for (int base = 0; base < deg; base += 4){
      int ii = base + (l & 3);
      int myidx = (int)(pairs[e0 + min(ii, deg - 1)] & 0x3FFFFu);
      int cc[4]; float m[4];
      #pragma unroll
      for (int q = 0; q < 4; ++q){
        cc[q] = __shfl(myidx, (g << 4) | q, 64);
        m[q] = (base + q < deg) ? 1.f : 0.f;
      }
      uint4 v[4];
      #pragma unroll
      for (int q = 0; q < 4; ++q)
        v[q] = *(const uint4*)(ubl + (size_t)cc[q] * DIM);
      #pragma unroll
      for (int q = 0; q < 4; ++q){
        a[0]=fmaf(m[q],bflo(v[q].x),a[0]); a[1]=fmaf(m[q],bfhi(v[q].x),a[1]);
        a[2]=fmaf(m[q],bflo(v[q].y),a[2]); a[3]=fmaf(m[q],bfhi(v[q].y),a[3]);
        a[4]=fmaf(m[q],bflo(v[q].z),a[4]); a[5]=fmaf(m[q],bfhi(v[q].z),a[5]);
        a[6]=fmaf(m[q],bflo(v[q].w),a[6]); a[7]=fmaf(m[q],bfhi(v[q].w),a[7]);
      }
    }
  } else {
    // unsorted overflow bucket: deterministic in-order scan filter
    unsigned p0 = bb[b], p1 = bb[b + 1];
    int lr = s & 255; deg = 0;
    for (unsigned e = p0; e < p1; ++e){
      unsigned p = pairs[e];
      if ((int)(p >> 18) == lr){
        ++deg;
        uint4 v = *(const uint4*)(ubl + (size_t)(p & 0x3FFFFu) * DIM);
        a[0]+=bflo(v.x); a[1]+=bfhi(v.x); a[2]+=bflo(v.y); a[3]+=bfhi(v.y);
        a[4]+=bflo(v.z); a[5]+=bfhi(v.z); a[6]+=bflo(v.w); a[7]+=bfhi(v.w);
      }
    }
  }
  float scl = deg ? 1.f / (float)deg : 0.f;
  uint4 o;
  o.x = f2bf(a[0]*scl) | (f2bf(a[1]*scl) << 16);
  o.y = f2bf(a[2]*scl) | (f2bf(a[3]*scl) << 16);
  o.z = f2bf(a[4]*scl) | (f2bf(a[5]*scl) << 16);
  o.w = f2bf(a[6]*scl) | (f2bf(a[7]*scl) << 16);
  *(uint4*)(aggb + (size_t)s * DIM + l * 8) = o;
}

// ---- k_h: h = leaky(ub@W1 + b1) in bf16, written IN PLACE over ub.
// Each wave owns rows tile*16..+15: all reads precede all writes in-wave -> race-free.
// LDS 32KB (W1 only) -> 4 blocks x 8 waves per CU.
__launch_bounds__(512)
__global__ void k_h(unsigned short* __restrict__ ubh,
                    const float* __restrict__ b1,
                    const unsigned short* __restrict__ wt){
  __shared__ __align__(16) char smem[32768];

  for (int c = threadIdx.x; c < 2048; c += 512){
    int i = c >> 4, kb = (c & 15) << 4;
    short8 v = *(const short8*)(wt + i * 128 + (kb >> 1));
    *(short8*)(smem + lbyte(i, kb)) = v;
  }
  __syncthreads();

  const int wid = threadIdx.x >> 6, lane = threadIdx.x & 63;
  const int l15 = lane & 15, kg = lane >> 4;
  const int tile = blockIdx.x * 8 + wid;
  if (tile >= NTILE) return;
  const int s = tile * 16 + l15;
  const size_t srow = (size_t)s * DIM;

  short8 ufr[4];
  #pragma unroll
  for (int ks = 0; ks < 4; ++ks)
    ufr[ks] = *(const short8*)(ubh + srow + ks * 32 + kg * 8);

  f32x4 hh[8];
  #pragma unroll
  for (int ft = 0; ft < 8; ++ft) hh[ft] = (f32x4){0.f,0.f,0.f,0.f};

  #pragma unroll
  for (int ks = 0; ks < 4; ++ks){
    #pragma unroll
    for (int ft = 0; ft < 8; ++ft){
      short8 af = *(const short8*)(smem + lbyte(ft * 16 + l15, ks * 64 + kg * 16));
      hh[ft] = __builtin_amdgcn_mfma_f32_16x16x32_bf16(af, ufr[ks], hh[ft], 0, 0, 0);
    }
  }

  #pragma unroll
  for (int ft = 0; ft < 8; ++ft){
    int f0 = ft * 16 + kg * 4;
    float4 bv = *(const float4*)(b1 + f0);
    short4v hv;
    hv[0] = (short)f2bf(lrelu(hh[ft][0] + bv.x));
    hv[1] = (short)f2bf(lrelu(hh[ft][1] + bv.y));
    hv[2] = (short)f2bf(lrelu(hh[ft][2] + bv.z));
    hv[3] = (short)f2bf(lrelu(hh[ft][3] + bv.w));
    *(short4v*)(ubh + srow + f0) = hv;
  }
}

// ---- k_out: out = h@W2 + (lrelu(aggn@Wp + bp) + b2).
// Spatial result becomes the INITIAL ACCUMULATOR of the W2 chain (no extra regs/add).
// LDS 64KB (W2,Wp) -> 2 blocks x 16 waves per CU; no LDS h-bounce.
__launch_bounds__(1024)
__global__ void k_out(const unsigned short* __restrict__ h,
                      const float* __restrict__ b2,
                      const float* __restrict__ bp,
                      const unsigned short* __restrict__ wt,
                      const unsigned short* __restrict__ aggb,
                      float* __restrict__ out){
  __shared__ __align__(16) char smem[65536];   // W2^T @0, Wp^T @32KB

  for (int c = threadIdx.x; c < 4096; c += 1024){
    int m = c >> 11, cc = c & 2047;
    int i = cc >> 4, kb = (cc & 15) << 4;
    short8 v = *(const short8*)(wt + (m + 1) * 16384 + i * 128 + (kb >> 1));
    *(short8*)(smem + m * 32768 + lbyte(i, kb)) = v;
  }
  __syncthreads();

  const int wid = threadIdx.x >> 6, lane = threadIdx.x & 63;
  const int l15 = lane & 15, kg = lane >> 4;
  const int tile = blockIdx.x * 16 + wid;
  if (tile >= NTILE) return;
  const int s = tile * 16 + l15;
  const size_t srow = (size_t)s * DIM;

  short8 hfr[4], afr[4];
  #pragma unroll
  for (int ks = 0; ks < 4; ++ks){
    hfr[ks] = *(const short8*)(h    + srow + ks * 32 + kg * 8);
    afr[ks] = *(const short8*)(aggb + srow + ks * 32 + kg * 8);
  }

  f32x4 acc[8];
  #pragma unroll
  for (int ft = 0; ft < 8; ++ft) acc[ft] = (f32x4){0.f,0.f,0.f,0.f};

  // spatial: acc = Wp^T @ aggn^T
  #pragma unroll
  for (int ks = 0; ks < 4; ++ks){
    #pragma unroll
    for (int ft = 0; ft < 8; ++ft){
      short8 af = *(const short8*)(smem + 32768 + lbyte(ft * 16 + l15, ks * 64 + kg * 16));
      acc[ft] = __builtin_amdgcn_mfma_f32_16x16x32_bf16(af, afr[ks], acc[ft], 0, 0, 0);
    }
  }
  // acc = lrelu(acc + bp) + b2  (becomes initial C of the W2 chain)
  #pragma unroll
  for (int ft = 0; ft < 8; ++ft){
    int f0 = ft * 16 + kg * 4;
    float4 pv = *(const float4*)(bp + f0);
    float4 bv = *(const float4*)(b2 + f0);
    acc[ft][0] = lrelu(acc[ft][0] + pv.x) + bv.x;
    acc[ft][1] = lrelu(acc[ft][1] + pv.y) + bv.y;
    acc[ft][2] = lrelu(acc[ft][2] + pv.z) + bv.z;
    acc[ft][3] = lrelu(acc[ft][3] + pv.w) + bv.w;
  }
  // acc += W2^T @ h^T
  #pragma unroll
  for (int ks = 0; ks < 4; ++ks){
    #pragma unroll
    for (int ft = 0; ft < 8; ++ft){
      short8 af = *(const short8*)(smem + lbyte(ft * 16 + l15, ks * 64 + kg * 16));
      acc[ft] = __builtin_amdgcn_mfma_f32_16x16x32_bf16(af, hfr[ks], acc[ft], 0, 0, 0);
    }
  }

  #pragma unroll
  for (int ft = 0; ft < 8; ++ft){
    int f0 = ft * 16 + kg * 4;
    *(f32x4*)(out + srow + f0) = acc[ft];
  }
}

extern "C" void kernel_launch(void* const* d_in, const int* in_sizes, int n_in,
                              void* d_out, int out_size, void* d_ws, size_t ws_size,
                              hipStream_t stream){
  (void)in_sizes; (void)n_in; (void)out_size; (void)ws_size;
  const float* u  = (const float*)d_in[0];
  const float* W1 = (const float*)d_in[1];
  const float* b1 = (const float*)d_in[2];
  const float* W2 = (const float*)d_in[3];
  const float* b2 = (const float*)d_in[4];
  const float* Wp = (const float*)d_in[5];
  const float* bp = (const float*)d_in[6];
  const int* row  = (const int*)d_in[7];
  const int* col  = (const int*)d_in[8];
  char* ws = (char*)d_ws;
  unsigned* bb     = (unsigned*)(ws + OFF_BB);
  unsigned* cur    = (unsigned*)(ws + OFF_CUR);
  unsigned* bcnt   = (unsigned*)(ws + OFF_BCNT);
  unsigned* pairs  = (unsigned*)(ws + OFF_PAIRS);
  unsigned* rowptr = (unsigned*)(ws + OFF_ROWPTR);
  unsigned short* wt    = (unsigned short*)(ws + OFF_WT);
  unsigned short* ubp   = (unsigned short*)(ws + OFF_UB);
  unsigned short* aggbp = (unsigned short*)(ws + OFF_AGGB);
  float* out = (float*)d_out;

  hipMemsetAsync(ws + OFF_BCNT, 0, 3136, stream);
  k_prep  <<<CAST_B + WT_B + CNT_B, 256, 0, stream>>>(u, ubp, W1, W2, Wp, wt, row, bcnt);
  k_bscan <<<1, 256, 0, stream>>>(bcnt, bb, cur);
  k_bfill <<<147, 512, 0, stream>>>(row, col, cur, pairs);
  k_sort  <<<NBKT, 256, 0, stream>>>(bb, pairs, rowptr);
  k_gather<<<12500, 256, 0, stream>>>(ubp, bb, rowptr, pairs, aggbp);
  k_h     <<<1563, 512, 0, stream>>>(ubp, b1, wt);                    // ub -> h in place
  k_out   <<<782, 1024, 0, stream>>>(ubp, b2, bp, wt, aggbp, out);
}

// Round 12
// 221.802 us; speedup vs baseline: 1.0300x; 1.0064x over previous
//
#include <hip/hip_runtime.h>

#define NSP 200000
#define NE  1200000
#define DIM 128
#define NTILE 12500        // NSP/16
#define NBKT  782          // ceil(NSP/256) row-range buckets
#define MAXE  2560         // per-bucket edge capacity for LDS sort (mean 1536, sigma 39)

#define CAST_B 12500
#define WT_B   192
#define CNT_B  586

typedef __attribute__((ext_vector_type(8))) short short8;
typedef __attribute__((ext_vector_type(4))) short short4v;
typedef __attribute__((ext_vector_type(4))) float f32x4;
typedef __attribute__((ext_vector_type(4))) unsigned u32x4;

// ---- workspace byte offsets (16B aligned); ws_size >= 133.7MB confirmed (R10 gate ran) ----
#define OFF_BB     0               // (NBKT+1)*4
#define OFF_CUR    3136            // NBKT*4
#define OFF_BCNT   6272            // NBKT*4
#define OFF_PAIRS  9408            // NE*4 packed (lr<<18)|col; sorted in place by k_sort
#define OFF_ROWPTR 4809408         // (NSP+1)*4
#define OFF_WT     5609424         // 3*128*128*2 bf16
#define OFF_UB     5707728         // NSP*128*2 bf16 u; OVERWRITTEN with h by k_h
#define OFF_AGGB   56907728        // NSP*128*2 bf16 agg (normalized)

__device__ __forceinline__ unsigned f2bf(float x){
  union { float f; unsigned u; } v; v.f = x;
  unsigned r = v.u + 0x7FFFu + ((v.u >> 16) & 1u);   // RNE
  return r >> 16;
}
__device__ __forceinline__ float bflo(unsigned v){ union{unsigned u;float f;}x; x.u = v << 16; return x.f; }
__device__ __forceinline__ float bfhi(unsigned v){ union{unsigned u;float f;}x; x.u = v & 0xffff0000u; return x.f; }
__device__ __forceinline__ float lrelu(float x){ return x > 0.f ? x : 0.2f * x; }

// swizzled byte offset inside a [rows][128] bf16 LDS tile (row stride 256B)
// full 4-bit slot XOR (R8: bank conflicts 5.4M -> 400K)
__device__ __forceinline__ int lbyte(int row, int kb){
  return row * 256 + (kb ^ ((row & 15) << 4));
}

// ---- prep: cast u->bf16 | transpose W->bf16 W^T | bucket histogram, by block range ----
__global__ void k_prep(const float* __restrict__ u, unsigned short* __restrict__ ub,
                       const float* __restrict__ W1, const float* __restrict__ W2,
                       const float* __restrict__ Wp, unsigned short* __restrict__ wt,
                       const int* __restrict__ row, unsigned* __restrict__ cnt){
  __shared__ unsigned hist[NBKT];
  int bid = blockIdx.x;
  if (bid < CAST_B){
    size_t i = (size_t)bid * 256 + threadIdx.x;
    const float4* p = (const float4*)(u + i * 8);
    float4 x0 = p[0], x1 = p[1];
    short8 v;
    v[0]=(short)f2bf(x0.x); v[1]=(short)f2bf(x0.y); v[2]=(short)f2bf(x0.z); v[3]=(short)f2bf(x0.w);
    v[4]=(short)f2bf(x1.x); v[5]=(short)f2bf(x1.y); v[6]=(short)f2bf(x1.z); v[7]=(short)f2bf(x1.w);
    *(short8*)(ub + i * 8) = v;
  } else if (bid < CAST_B + WT_B){
    int i = (bid - CAST_B) * 256 + threadIdx.x;
    int m = i >> 14, e = i & 16383;
    int k = e >> 7, c = e & 127;
    const float* W = (m == 0) ? W1 : (m == 1) ? W2 : Wp;
    wt[m * 16384 + c * 128 + k] = (unsigned short)f2bf(W[e]);
  } else {
    int cb = bid - CAST_B - WT_B;
    for (int i = threadIdx.x; i < NBKT; i += 256) hist[i] = 0;
    __syncthreads();
    #pragma unroll
    for (int j = 0; j < 8; ++j){
      int i = cb * 2048 + j * 256 + threadIdx.x;
      if (i < NE) atomicAdd(&hist[row[i] >> 8], 1u);
    }
    __syncthreads();
    for (int i = threadIdx.x; i < NBKT; i += 256){
      unsigned v = hist[i];
      if (v) atomicAdd(&cnt[i], v);
    }
  }
}

// ---- exclusive scan of NBKT counts (1 block) -> bb, cur ----
__global__ void k_bscan(const unsigned* __restrict__ cnt, unsigned* __restrict__ bb,
                        unsigned* __restrict__ cur){
  __shared__ unsigned wsum[4];
  int t = threadIdx.x, lane = t & 63, w = t >> 6;
  unsigned c4[4], s = 0;
  #pragma unroll
  for (int j = 0; j < 4; ++j){
    int idx = t * 4 + j;
    c4[j] = (idx < NBKT) ? cnt[idx] : 0u;
    s += c4[j];
  }
  unsigned inc = s;
  #pragma unroll
  for (int off = 1; off < 64; off <<= 1){
    unsigned n = __shfl_up(inc, (unsigned)off, 64);
    if (lane >= off) inc += n;
  }
  if (lane == 63) wsum[w] = inc;
  __syncthreads();
  unsigned prior = 0;
  for (int i = 0; i < w; ++i) prior += wsum[i];
  unsigned excl = prior + (inc - s);
  #pragma unroll
  for (int j = 0; j < 4; ++j){
    int idx = t * 4 + j;
    if (idx < NBKT){
      bb[idx] = excl; cur[idx] = excl;
      excl += c4[j];
      if (idx == NBKT - 1) bb[NBKT] = excl;
    }
  }
}

// ---- bin edges into bucket regions (block-batched cursor grabs) ----
__global__ void k_bfill(const int* __restrict__ row, const int* __restrict__ col,
                        unsigned* __restrict__ cur, unsigned* __restrict__ pairs){
  __shared__ unsigned hist[NBKT], base[NBKT];
  for (int i = threadIdx.x; i < NBKT; i += 512) hist[i] = 0;
  __syncthreads();
  int r[16], c[16];
  #pragma unroll
  for (int j = 0; j < 16; ++j){
    int i = blockIdx.x * 8192 + j * 512 + threadIdx.x;
    r[j] = -1;
    if (i < NE){ r[j] = row[i]; c[j] = col[i]; atomicAdd(&hist[r[j] >> 8], 1u); }
  }
  __syncthreads();
  for (int i = threadIdx.x; i < NBKT; i += 512){
    unsigned n = hist[i];
    base[i] = n ? atomicAdd(&cur[i], n) : 0u;
    hist[i] = 0;
  }
  __syncthreads();
  #pragma unroll
  for (int j = 0; j < 16; ++j){
    if (r[j] >= 0){
      int b = r[j] >> 8;
      unsigned pos = base[b] + atomicAdd(&hist[b], 1u);
      pairs[pos] = ((unsigned)(r[j] & 255) << 18) | (unsigned)c[j];
    }
  }
}

// ---- per bucket: counting-sort pairs by local row IN PLACE, emit global CSR rowptr ----
__launch_bounds__(256)
__global__ void k_sort(const unsigned* __restrict__ bb,
                       unsigned* __restrict__ pairs,
                       unsigned* __restrict__ rowptr){
  __shared__ unsigned raw[MAXE], srt[MAXE];
  __shared__ unsigned hist[256], start[257], cur[256];
  __shared__ unsigned wsum[4];
  const int b = blockIdx.x, t = threadIdx.x;
  const int lane = t & 63, w = t >> 6;
  const unsigned base0 = bb[b], cnt = bb[b + 1] - base0;
  hist[t] = 0; cur[t] = 0;
  __syncthreads();

  if (cnt <= MAXE){
    for (unsigned i = t; i < cnt; i += 256){
      unsigned p = pairs[base0 + i];
      raw[i] = p;
      atomicAdd(&hist[p >> 18], 1u);
    }
  } else {
    for (unsigned i = t; i < cnt; i += 256)
      atomicAdd(&hist[pairs[base0 + i] >> 18], 1u);
  }
  __syncthreads();
  unsigned v = hist[t], inc = v;
  #pragma unroll
  for (int off = 1; off < 64; off <<= 1){
    unsigned n = __shfl_up(inc, (unsigned)off, 64);
    if (lane >= off) inc += n;
  }
  if (lane == 63) wsum[w] = inc;
  __syncthreads();
  unsigned prior = 0;
  for (int i = 0; i < w; ++i) prior += wsum[i];
  start[t] = prior + inc - v;
  if (t == 255) start[256] = prior + inc;
  __syncthreads();

  {
    int idx = b * 256 + t;
    if (idx <= NSP) rowptr[idx] = base0 + start[t];
  }

  if (cnt <= MAXE){
    for (unsigned i = t; i < cnt; i += 256){
      unsigned p = raw[i], lr = p >> 18;
      unsigned slot = start[lr] + atomicAdd(&cur[lr], 1u);
      srt[slot] = p & 0x3FFFFu;
    }
    __syncthreads();
    for (unsigned i = t; i < cnt; i += 256) pairs[base0 + i] = srt[i];
  }
  // overflow buckets (statistically unreachable): left unsorted; gather falls back
}

// ---- gather: 4 spots per wave, 16 lanes x uint4 (16B) per spot row (R9-proven path).
// NT hints: pairs read + aggb write are streaming -> bypass L2 allocation, keep L2 for ub rows.
__launch_bounds__(256)
__global__ void k_gather(const unsigned short* __restrict__ ub,
                         const unsigned* __restrict__ bb,
                         const unsigned* __restrict__ rowptr,
                         const unsigned* __restrict__ pairs,
                         unsigned short* __restrict__ aggb){
  const int wid = (blockIdx.x * 256 + threadIdx.x) >> 6;   // 0..49999
  const int lane = threadIdx.x & 63;
  const int g = lane >> 4, l = lane & 15;
  const int s = wid * 4 + g;                               // spot, < NSP exactly
  const int b = s >> 8;
  const unsigned e0 = rowptr[s], e1 = rowptr[s + 1];
  int deg = (int)(e1 - e0);
  const unsigned bc = bb[b + 1] - bb[b];
  float a[8];
  #pragma unroll
  for (int q = 0; q < 8; ++q) a[q] = 0.f;
  const unsigned short* ubl = ub + (size_t)l * 8;

  if (bc <= MAXE){
    for (int base = 0; base < deg; base += 4){
      int ii = base + (l & 3);
      int myidx = (int)(__builtin_nontemporal_load(&pairs[e0 + min(ii, deg - 1)]) & 0x3FFFFu);
      int cc[4]; float m[4];
      #pragma unroll
      for (int q = 0; q < 4; ++q){
        cc[q] = __shfl(myidx, (g << 4) | q, 64);
        m[q] = (base + q < deg) ? 1.f : 0.f;
      }
      uint4 v[4];
      #pragma unroll
      for (int q = 0; q < 4; ++q)
        v[q] = *(const uint4*)(ubl + (size_t)cc[q] * DIM);
      #pragma unroll
      for (int q = 0; q < 4; ++q){
        a[0]=fmaf(m[q],bflo(v[q].x),a[0]); a[1]=fmaf(m[q],bfhi(v[q].x),a[1]);
        a[2]=fmaf(m[q],bflo(v[q].y),a[2]); a[3]=fmaf(m[q],bfhi(v[q].y),a[3]);
        a[4]=fmaf(m[q],bflo(v[q].z),a[4]); a[5]=fmaf(m[q],bfhi(v[q].z),a[5]);
        a[6]=fmaf(m[q],bflo(v[q].w),a[6]); a[7]=fmaf(m[q],bfhi(v[q].w),a[7]);
      }
    }
  } else {
    // unsorted overflow bucket: deterministic in-order scan filter
    unsigned p0 = bb[b], p1 = bb[b + 1];
    int lr = s & 255; deg = 0;
    for (unsigned e = p0; e < p1; ++e){
      unsigned p = pairs[e];
      if ((int)(p >> 18) == lr){
        ++deg;
        uint4 v = *(const uint4*)(ubl + (size_t)(p & 0x3FFFFu) * DIM);
        a[0]+=bflo(v.x); a[1]+=bfhi(v.x); a[2]+=bflo(v.y); a[3]+=bfhi(v.y);
        a[4]+=bflo(v.z); a[5]+=bfhi(v.z); a[6]+=bflo(v.w); a[7]+=bfhi(v.w);
      }
    }
  }
  float scl = deg ? 1.f / (float)deg : 0.f;
  u32x4 o;
  o.x = f2bf(a[0]*scl) | (f2bf(a[1]*scl) << 16);
  o.y = f2bf(a[2]*scl) | (f2bf(a[3]*scl) << 16);
  o.z = f2bf(a[4]*scl) | (f2bf(a[5]*scl) << 16);
  o.w = f2bf(a[6]*scl) | (f2bf(a[7]*scl) << 16);
  __builtin_nontemporal_store(o, (u32x4*)(aggb + (size_t)s * DIM + l * 8));
}

// ---- k_h: h = leaky(ub@W1 + b1) in bf16, written IN PLACE over ub.
// Each wave owns rows tile*16..+15: all reads precede all writes in-wave -> race-free.
__launch_bounds__(512)
__global__ void k_h(unsigned short* __restrict__ ubh,
                    const float* __restrict__ b1,
                    const unsigned short* __restrict__ wt){
  __shared__ __align__(16) char smem[32768];

  for (int c = threadIdx.x; c < 2048; c += 512){
    int i = c >> 4, kb = (c & 15) << 4;
    short8 v = *(const short8*)(wt + i * 128 + (kb >> 1));
    *(short8*)(smem + lbyte(i, kb)) = v;
  }
  __syncthreads();

  const int wid = threadIdx.x >> 6, lane = threadIdx.x & 63;
  const int l15 = lane & 15, kg = lane >> 4;
  const int tile = blockIdx.x * 8 + wid;
  if (tile >= NTILE) return;
  const int s = tile * 16 + l15;
  const size_t srow = (size_t)s * DIM;

  short8 ufr[4];
  #pragma unroll
  for (int ks = 0; ks < 4; ++ks)
    ufr[ks] = *(const short8*)(ubh + srow + ks * 32 + kg * 8);

  f32x4 hh[8];
  #pragma unroll
  for (int ft = 0; ft < 8; ++ft) hh[ft] = (f32x4){0.f,0.f,0.f,0.f};

  #pragma unroll
  for (int ks = 0; ks < 4; ++ks){
    #pragma unroll
    for (int ft = 0; ft < 8; ++ft){
      short8 af = *(const short8*)(smem + lbyte(ft * 16 + l15, ks * 64 + kg * 16));
      hh[ft] = __builtin_amdgcn_mfma_f32_16x16x32_bf16(af, ufr[ks], hh[ft], 0, 0, 0);
    }
  }

  #pragma unroll
  for (int ft = 0; ft < 8; ++ft){
    int f0 = ft * 16 + kg * 4;
    float4 bv = *(const float4*)(b1 + f0);
    short4v hv;
    hv[0] = (short)f2bf(lrelu(hh[ft][0] + bv.x));
    hv[1] = (short)f2bf(lrelu(hh[ft][1] + bv.y));
    hv[2] = (short)f2bf(lrelu(hh[ft][2] + bv.z));
    hv[3] = (short)f2bf(lrelu(hh[ft][3] + bv.w));
    *(short4v*)(ubh + srow + f0) = hv;
  }
}

// ---- k_out: out = h@W2 + (lrelu(aggn@Wp + bp) + b2); spatial result = initial accumulator.
// NT store for out: 102MB stream, keep L2 for the h/aggb read streams.
__launch_bounds__(1024)
__global__ void k_out(const unsigned short* __restrict__ h,
                      const float* __restrict__ b2,
                      const float* __restrict__ bp,
                      const unsigned short* __restrict__ wt,
                      const unsigned short* __restrict__ aggb,
                      float* __restrict__ out){
  __shared__ __align__(16) char smem[65536];   // W2^T @0, Wp^T @32KB

  for (int c = threadIdx.x; c < 4096; c += 1024){
    int m = c >> 11, cc = c & 2047;
    int i = cc >> 4, kb = (cc & 15) << 4;
    short8 v = *(const short8*)(wt + (m + 1) * 16384 + i * 128 + (kb >> 1));
    *(short8*)(smem + m * 32768 + lbyte(i, kb)) = v;
  }
  __syncthreads();

  const int wid = threadIdx.x >> 6, lane = threadIdx.x & 63;
  const int l15 = lane & 15, kg = lane >> 4;
  const int tile = blockIdx.x * 16 + wid;
  if (tile >= NTILE) return;
  const int s = tile * 16 + l15;
  const size_t srow = (size_t)s * DIM;

  short8 hfr[4], afr[4];
  #pragma unroll
  for (int ks = 0; ks < 4; ++ks){
    hfr[ks] = *(const short8*)(h    + srow + ks * 32 + kg * 8);
    afr[ks] = *(const short8*)(aggb + srow + ks * 32 + kg * 8);
  }

  f32x4 acc[8];
  #pragma unroll
  for (int ft = 0; ft < 8; ++ft) acc[ft] = (f32x4){0.f,0.f,0.f,0.f};

  // spatial: acc = Wp^T @ aggn^T
  #pragma unroll
  for (int ks = 0; ks < 4; ++ks){
    #pragma unroll
    for (int ft = 0; ft < 8; ++ft){
      short8 af = *(const short8*)(smem + 32768 + lbyte(ft * 16 + l15, ks * 64 + kg * 16));
      acc[ft] = __builtin_amdgcn_mfma_f32_16x16x32_bf16(af, afr[ks], acc[ft], 0, 0, 0);
    }
  }
  // acc = lrelu(acc + bp) + b2  (becomes initial C of the W2 chain)
  #pragma unroll
  for (int ft = 0; ft < 8; ++ft){
    int f0 = ft * 16 + kg * 4;
    float4 pv = *(const float4*)(bp + f0);
    float4 bv = *(const float4*)(b2 + f0);
    acc[ft][0] = lrelu(acc[ft][0] + pv.x) + bv.x;
    acc[ft][1] = lrelu(acc[ft][1] + pv.y) + bv.y;
    acc[ft][2] = lrelu(acc[ft][2] + pv.z) + bv.z;
    acc[ft][3] = lrelu(acc[ft][3] + pv.w) + bv.w;
  }
  // acc += W2^T @ h^T
  #pragma unroll
  for (int ks = 0; ks < 4; ++ks){
    #pragma unroll
    for (int ft = 0; ft < 8; ++ft){
      short8 af = *(const short8*)(smem + lbyte(ft * 16 + l15, ks * 64 + kg * 16));
      acc[ft] = __builtin_amdgcn_mfma_f32_16x16x32_bf16(af, hfr[ks], acc[ft], 0, 0, 0);
    }
  }

  #pragma unroll
  for (int ft = 0; ft < 8; ++ft){
    int f0 = ft * 16 + kg * 4;
    __builtin_nontemporal_store(acc[ft], (f32x4*)(out + srow + f0));
  }
}

extern "C" void kernel_launch(void* const* d_in, const int* in_sizes, int n_in,
                              void* d_out, int out_size, void* d_ws, size_t ws_size,
                              hipStream_t stream){
  (void)in_sizes; (void)n_in; (void)out_size; (void)ws_size;
  const float* u  = (const float*)d_in[0];
  const float* W1 = (const float*)d_in[1];
  const float* b1 = (const float*)d_in[2];
  const float* W2 = (const float*)d_in[3];
  const float* b2 = (const float*)d_in[4];
  const float* Wp = (const float*)d_in[5];
  const float* bp = (const float*)d_in[6];
  const int* row  = (const int*)d_in[7];
  const int* col  = (const int*)d_in[8];
  char* ws = (char*)d_ws;
  unsigned* bb     = (unsigned*)(ws + OFF_BB);
  unsigned* cur    = (unsigned*)(ws + OFF_CUR);
  unsigned* bcnt   = (unsigned*)(ws + OFF_BCNT);
  unsigned* pairs  = (unsigned*)(ws + OFF_PAIRS);
  unsigned* rowptr = (unsigned*)(ws + OFF_ROWPTR);
  unsigned short* wt    = (unsigned short*)(ws + OFF_WT);
  unsigned short* ubp   = (unsigned short*)(ws + OFF_UB);
  unsigned short* aggbp = (unsigned short*)(ws + OFF_AGGB);
  float* out = (float*)d_out;

  hipMemsetAsync(ws + OFF_BCNT, 0, 3136, stream);
  k_prep  <<<CAST_B + WT_B + CNT_B, 256, 0, stream>>>(u, ubp, W1, W2, Wp, wt, row, bcnt);
  k_bscan <<<1, 256, 0, stream>>>(bcnt, bb, cur);
  k_bfill <<<147, 512, 0, stream>>>(row, col, cur, pairs);
  k_sort  <<<NBKT, 256, 0, stream>>>(bb, pairs, rowptr);
  k_gather<<<12500, 256, 0, stream>>>(ubp, bb, rowptr, pairs, aggbp);
  k_h     <<<1563, 512, 0, stream>>>(ubp, b1, wt);                    // ub -> h in place
  k_out   <<<782, 1024, 0, stream>>>(ubp, b2, bp, wt, aggbp, out);
}